// Round 1
// baseline (1268.779 us; speedup 1.0000x reference)
//
#include <hip/hip_runtime.h>

typedef unsigned short u16;
typedef unsigned int u32;
typedef __attribute__((ext_vector_type(8))) short short8;   // 8 bf16 (4 VGPRs) MFMA operand
typedef __attribute__((ext_vector_type(4))) float f32x4;    // MFMA accumulator

#define GLOBAL_AS __attribute__((address_space(1)))
#define LDS_AS __attribute__((address_space(3)))

// ---- helpers -------------------------------------------------------------
__device__ __forceinline__ u16 f2bf(float f) {           // RNE float->bf16
  u32 u = __float_as_uint(f);
  u += 0x7fffu + ((u >> 16) & 1u);
  return (u16)(u >> 16);
}
__device__ __forceinline__ float bflo(u32 u) { return __uint_as_float(u << 16); }
__device__ __forceinline__ float bfhi(u32 u) { return __uint_as_float(u & 0xffff0000u); }

__device__ __forceinline__ void gload_lds16(const void* g, void* l) {
  __builtin_amdgcn_global_load_lds((const GLOBAL_AS void*)g, (LDS_AS void*)l, 16, 0, 0);
}

// ---- kernel 1: fp32 -> bf16 conversion of X=[img;text], W=[Wq;Wk], bias --
// X bf16 lands in d_out second half; Wcat/bcat in d_ws.
__global__ __launch_bounds__(256) void convert_all(
    const float4* __restrict__ img4, const float4* __restrict__ text4,
    const float4* __restrict__ wq4, const float4* __restrict__ wk4,
    const float4* __restrict__ bq4, const float4* __restrict__ bk4,
    ushort4* __restrict__ xbf4, ushort4* __restrict__ wcat4,
    float4* __restrict__ bcat4) {
  size_t id = (size_t)blockIdx.x * 256 + threadIdx.x;
  if (id < 25165824) {                       // X: img (12582912 f4) then text
    float4 v = (id < 12582912) ? img4[id] : text4[id - 12582912];
    ushort4 r; r.x = f2bf(v.x); r.y = f2bf(v.y); r.z = f2bf(v.z); r.w = f2bf(v.w);
    xbf4[id] = r;
  } else if (id < 26214400) {                // W: Wq (524288 f4) then Wk
    size_t j = id - 25165824;
    float4 v = (j < 524288) ? wq4[j] : wk4[j - 524288];
    ushort4 r; r.x = f2bf(v.x); r.y = f2bf(v.y); r.z = f2bf(v.z); r.w = f2bf(v.w);
    wcat4[j] = r;
  } else {                                   // bias: bq (256 f4) then bk
    size_t j = id - 26214400;                // j < 512
    bcat4[j] = (j < 256) ? bq4[j] : bk4[j - 256];
  }
}

// ---- kernel 2: bf16 MFMA GEMM ---------------------------------------------
// C[m,n] = sum_d X[m,d]*W[n,d] + bias[n]; M=49152, N=2048, K=2048.
// 128x128 tile, BK=32, 4 waves of 64x64, 16x16x32 bf16 MFMA, global_load_lds x16.
// Output written bf16 into batch-interleaved QK layout in d_out first half:
//   batch block of 12 rows x 1024: [Q_i(0-2) K_i(3-5) Q_t(6-8) K_t(9-11)].
__global__ __launch_bounds__(256) void gemm_qk(
    const u16* __restrict__ X, const u16* __restrict__ W,
    const float* __restrict__ bias, u16* __restrict__ QK) {
  __shared__ __align__(16) u16 As[128 * 32];  // 8 KB
  __shared__ __align__(16) u16 Bs[128 * 32];  // 8 KB
  const int t = threadIdx.x;
  const int lane = t & 63;
  const int wv = t >> 6;
  const int m0 = blockIdx.y * 128;
  const int n0 = blockIdx.x * 128;
  const int wm = (wv & 1) * 64;
  const int wn = (wv >> 1) * 64;
  const int fm = lane & 15;   // MFMA A/B free index within 16
  const int fq = lane >> 4;   // quad -> k chunk (A/B), row group (C)

  // staging: chunk c=(wv*2+i)*64+lane covers 16B; row=c>>2, kchunk=c&3
  const int r0 = (wv * 2 + 0) * 16 + (lane >> 2);
  const int r1 = (wv * 2 + 1) * 16 + (lane >> 2);
  const int kc8 = (lane & 3) * 8;
  const u16* gA0 = X + (size_t)(m0 + r0) * 2048 + kc8;
  const u16* gA1 = X + (size_t)(m0 + r1) * 2048 + kc8;
  const u16* gB0 = W + (size_t)(n0 + r0) * 2048 + kc8;
  const u16* gB1 = W + (size_t)(n0 + r1) * 2048 + kc8;
  u16* lA0 = &As[(wv * 2 + 0) * 512];  // wave-uniform LDS bases
  u16* lA1 = &As[(wv * 2 + 1) * 512];
  u16* lB0 = &Bs[(wv * 2 + 0) * 512];
  u16* lB1 = &Bs[(wv * 2 + 1) * 512];

  const f32x4 zero = {0.f, 0.f, 0.f, 0.f};
  f32x4 acc[4][4];
#pragma unroll
  for (int i = 0; i < 4; i++)
#pragma unroll
    for (int j = 0; j < 4; j++) acc[i][j] = zero;

  for (int kb = 0; kb < 2048; kb += 32) {
    __syncthreads();  // protect LDS from previous iteration's readers
    gload_lds16(gA0 + kb, lA0);
    gload_lds16(gA1 + kb, lA1);
    gload_lds16(gB0 + kb, lB0);
    gload_lds16(gB1 + kb, lB1);
    __syncthreads();  // drains vmcnt(0): staged data visible

    short8 a[4], b[4];
#pragma unroll
    for (int i = 0; i < 4; i++) {
      a[i] = *(const short8*)&As[(wm + i * 16 + fm) * 32 + fq * 8];
      b[i] = *(const short8*)&Bs[(wn + i * 16 + fm) * 32 + fq * 8];
    }
#pragma unroll
    for (int i = 0; i < 4; i++)
#pragma unroll
      for (int j = 0; j < 4; j++)
        acc[i][j] = __builtin_amdgcn_mfma_f32_16x16x32_bf16(a[i], b[j], acc[i][j], 0, 0, 0);
  }

  // epilogue: bias + bf16 convert + batch-interleaved scatter
  float bn[4];
#pragma unroll
  for (int j = 0; j < 4; j++) bn[j] = bias[n0 + wn + j * 16 + fm];

#pragma unroll
  for (int i = 0; i < 4; i++) {
#pragma unroll
    for (int r = 0; r < 4; r++) {
      int mg = m0 + wm + i * 16 + fq * 4 + r;  // C row = quad*4 + reg
      unsigned bb, idx, base;
      if (mg < 24576) { bb = (unsigned)mg / 3u; idx = (unsigned)mg - bb * 3u; base = 0u; }
      else { unsigned mt = (unsigned)mg - 24576u; bb = mt / 3u; idx = mt - bb * 3u; base = 6u; }
      size_t rowbase = (size_t)bb * 12288 + (size_t)(base + idx) * 1024;
#pragma unroll
      for (int j = 0; j < 4; j++) {
        int ng = n0 + wn + j * 16 + fm;        // C col = lane&15
        size_t pos = rowbase + ((ng & 1024) ? 3072 : 0) + (ng & 1023);
        QK[pos] = f2bf(acc[i][j][r] + bn[j]);
      }
    }
  }
}

// ---- kernel 3: fused logits -> softmax -> j_lin -> bilinear -> outputs ----
// One block (256 thr) per batch. Reads its 12x1024 bf16 QK block (aliased with
// out_i region it later overwrites; ordering enforced by data deps + barrier).
__global__ __launch_bounds__(256) void fuse_out(
    const float* __restrict__ img, const float* __restrict__ text,
    const float* __restrict__ Wj, const float* __restrict__ bjp,
    const float* __restrict__ Wb, float* __restrict__ out) {
  const int t = threadIdx.x;
  const int lane = t & 63;
  const int wv = t >> 6;
  const int b = blockIdx.x;

  const uint2* qkp = (const uint2*)((const char*)out + (size_t)b * 24576);

  // each thread: 4 consecutive k of each of the 12 rows
  float R[12][4];
#pragma unroll
  for (int r = 0; r < 12; r++) {
    uint2 u = qkp[r * 256 + t];
    R[r][0] = bflo(u.x); R[r][1] = bfhi(u.x);
    R[r][2] = bflo(u.y); R[r][3] = bfhi(u.y);
  }
  float acc[27];
#pragma unroll
  for (int a = 0; a < 27; a++) acc[a] = 0.f;
#pragma unroll
  for (int q = 0; q < 3; q++)
#pragma unroll
    for (int s = 0; s < 3; s++)
#pragma unroll
      for (int j = 0; j < 4; j++) {
        acc[q * 3 + s]      += R[q][j]     * R[9 + s][j];  // it: Qi.Kt
        acc[9 + q * 3 + s]  += R[q][j]     * R[3 + s][j];  // ii: Qi.Ki
        acc[18 + q * 3 + s] += R[6 + q][j] * R[9 + s][j];  // tt: Qt.Kt
      }
  // wave allreduce then cross-wave via LDS
#pragma unroll
  for (int a = 0; a < 27; a++) {
    float v = acc[a];
#pragma unroll
    for (int off = 32; off > 0; off >>= 1) v += __shfl_xor(v, off, 64);
    acc[a] = v;
  }
  __shared__ float red[4][27];
  if (lane == 0) {
#pragma unroll
    for (int a = 0; a < 27; a++) red[wv][a] = acc[a];
  }
  __syncthreads();  // also fences: all QK loads precede the out stores below
  float S[27];
#pragma unroll
  for (int a = 0; a < 27; a++) S[a] = red[0][a] + red[1][a] + red[2][a] + red[3][a];

  // softmax over s, then * 1/sqrt(1024)
  float P[27];
#pragma unroll
  for (int m = 0; m < 3; m++)
#pragma unroll
    for (int q = 0; q < 3; q++) {
      int o0 = m * 9 + q * 3;
      float x = S[o0], y = S[o0 + 1], z = S[o0 + 2];
      float mx = fmaxf(x, fmaxf(y, z));
      float e0 = __expf(x - mx), e1 = __expf(y - mx), e2 = __expf(z - mx);
      float inv = 0.03125f / (e0 + e1 + e2);
      P[o0] = e0 * inv; P[o0 + 1] = e1 * inv; P[o0 + 2] = e2 * inv;
    }
  // j_lin on each map: J[map][q][o] = bj[o] + sum_s Wj[o,s]*P[map][q][s]
  float J[3][3][3];
#pragma unroll
  for (int m = 0; m < 3; m++)
#pragma unroll
    for (int q = 0; q < 3; q++)
#pragma unroll
      for (int o = 0; o < 3; o++)
        J[m][q][o] = bjp[o] + Wj[o * 3 + 0] * P[m * 9 + q * 3 + 0]
                            + Wj[o * 3 + 1] * P[m * 9 + q * 3 + 1]
                            + Wj[o * 3 + 2] * P[m * 9 + q * 3 + 2];
  // bilinear: ai = B(j_it, j_ii), at = B(j_it, j_tt)
  float ai[3][3], at[3][3];
#pragma unroll
  for (int q = 0; q < 3; q++)
#pragma unroll
    for (int o = 0; o < 3; o++) {
      float s1 = 0.f, s2 = 0.f;
#pragma unroll
      for (int i = 0; i < 3; i++) {
        float a1 = J[0][q][i];
#pragma unroll
        for (int j = 0; j < 3; j++) {
          float w = Wb[(o * 3 + i) * 3 + j];
          s1 += a1 * w * J[1][q][j];
          s2 += a1 * w * J[2][q][j];
        }
      }
      ai[q][o] = s1; at[q][o] = s2;
    }

  // outputs: out_i[q,d] = sum_s ai[q][s]*img[s,d] (fp32 inputs), same for text
  const float4* im4 = (const float4*)(img + (size_t)b * 6144);
  const float4* tx4 = (const float4*)(text + (size_t)b * 6144);
  float4* oi4 = (float4*)out + (size_t)b * 1536;
  float4* ot4 = (float4*)out + 12582912 + (size_t)b * 1536;
#pragma unroll
  for (int rep = 0; rep < 2; rep++) {
    int col = rep * 256 + t;
    float4 x0 = im4[col], x1 = im4[512 + col], x2 = im4[1024 + col];
    float4 y0 = tx4[col], y1 = tx4[512 + col], y2 = tx4[1024 + col];
#pragma unroll
    for (int q = 0; q < 3; q++) {
      float4 o1, o2;
      o1.x = ai[q][0] * x0.x + ai[q][1] * x1.x + ai[q][2] * x2.x;
      o1.y = ai[q][0] * x0.y + ai[q][1] * x1.y + ai[q][2] * x2.y;
      o1.z = ai[q][0] * x0.z + ai[q][1] * x1.z + ai[q][2] * x2.z;
      o1.w = ai[q][0] * x0.w + ai[q][1] * x1.w + ai[q][2] * x2.w;
      oi4[q * 512 + col] = o1;
      o2.x = at[q][0] * y0.x + at[q][1] * y1.x + at[q][2] * y2.x;
      o2.y = at[q][0] * y0.y + at[q][1] * y1.y + at[q][2] * y2.y;
      o2.z = at[q][0] * y0.z + at[q][1] * y1.z + at[q][2] * y2.z;
      o2.w = at[q][0] * y0.w + at[q][1] * y1.w + at[q][2] * y2.w;
      ot4[q * 512 + col] = o2;
    }
  }
}

// ---- launch ---------------------------------------------------------------
extern "C" void kernel_launch(void* const* d_in, const int* in_sizes, int n_in,
                              void* d_out, int out_size, void* d_ws, size_t ws_size,
                              hipStream_t stream) {
  const float* img  = (const float*)d_in[0];
  const float* text = (const float*)d_in[1];
  const float* Wq   = (const float*)d_in[2];
  const float* bq   = (const float*)d_in[3];
  const float* Wk   = (const float*)d_in[4];
  const float* bk   = (const float*)d_in[5];
  const float* Wj   = (const float*)d_in[6];
  const float* bj   = (const float*)d_in[7];
  const float* Wbil = (const float*)d_in[8];
  float* out = (float*)d_out;

  // workspace: Wcat bf16 (8,388,608 B) + bcat f32 (8 KB)  => needs ~8.4 MB
  u16* Wcat = (u16*)d_ws;
  float* bcat = (float*)((char*)d_ws + 8388608);
  // d_out second half hosts X=[img;text] bf16; first half hosts QK bf16
  u16* Xbf = (u16*)(out + 50331648);
  u16* QK  = (u16*)out;

  convert_all<<<102402, 256, 0, stream>>>(
      (const float4*)img, (const float4*)text, (const float4*)Wq,
      (const float4*)Wk, (const float4*)bq, (const float4*)bk,
      (ushort4*)Xbf, (ushort4*)Wcat, (float4*)bcat);

  dim3 g(16, 384, 1);  // x = n-tile (fast) so A-tile reused by 16 consecutive blocks
  gemm_qk<<<g, 256, 0, stream>>>(Xbf, Wcat, bcat, QK);

  fuse_out<<<8192, 256, 0, stream>>>(img, text, Wj, bj, Wbil, out);
}